// Round 23
// baseline (219.192 us; speedup 1.0000x reference)
//
#include <hip/hip_runtime.h>
#include <hip/hip_bf16.h>

// PartitionedNormalization: per-domain BN stats (training mode) + affine.
// out[B][128] f32 = (gg+dg[s])*(x-mean[s])*rsqrt(var[s]+eps) + (gb+db[s])
//
// R23 = R18 (best, 90.9us) + ONE change: reduce2+finalize merged into a
// single 4-block pn_stats kernel (reduces all 512 partial rows directly;
// drops partials2, one launch + gap). R22 producer/consumer reverted
// (108.6us — staging overhead > RMW-chain saving; 9th pass-1 variant).

#define DIM 128
#define NDOM 8
#define PENT (NDOM + 2 * NDOM * DIM)  // 8 counts + 1024 sums + 1024 sqsums = 2056
#define EPSV 1e-3f
#define WREG 2048  // per half-wave region (floats): sums[8][128] | sqs[8][128]

// ---------------- pass 1: half-wave-private LDS accumulation (R18, verified) ----------------
__global__ __launch_bounds__(256) void pn_reduce(const float4* __restrict__ x4,
                                                 const int* __restrict__ seg,
                                                 float* __restrict__ partials,
                                                 int rowsPerBlock) {
  __shared__ float acc[8 * WREG];  // 64 KB -> 2 blocks/CU
  __shared__ float lcnt[NDOM];
  const int tid = threadIdx.x;
  const int w = tid >> 6;  // wave 0..3
  const int l = tid & 63;
  const int h = l >> 5;    // half-wave: row parity
  const int g = l & 31;    // float4 col group
  float* reg = acc + (w * 2 + h) * WREG;  // half-wave private

  for (int i = tid; i < 2 * WREG; i += 256)
    ((float4*)acc)[i] = make_float4(0.f, 0.f, 0.f, 0.f);
  if (tid < NDOM) lcnt[tid] = 0.f;
  __syncthreads();

  const int rowsPerWave = rowsPerBlock >> 2;  // 128 at NB=512
  const int row0 = blockIdx.x * rowsPerBlock + w * rowsPerWave;

#define RMW(S, V)                                    \
  {                                                  \
    float* bs = reg + (S) * 128 + g * 4;             \
    float* bq = bs + NDOM * DIM;                     \
    float4 os = *(float4*)bs;                        \
    float4 oq = *(float4*)bq;                        \
    os.x += (V).x;                                   \
    os.y += (V).y;                                   \
    os.z += (V).z;                                   \
    os.w += (V).w;                                   \
    oq.x = fmaf((V).x, (V).x, oq.x);                 \
    oq.y = fmaf((V).y, (V).y, oq.y);                 \
    oq.z = fmaf((V).z, (V).z, oq.z);                 \
    oq.w = fmaf((V).w, (V).w, oq.w);                 \
    *(float4*)bs = os;                               \
    *(float4*)bq = oq;                               \
  }
  for (int it = 0; it < rowsPerWave; it += 16) {
    const int r = row0 + it;
    const int4 sgA = *(const int4*)(seg + r);       // rows r..r+3
    const int4 sgB = *(const int4*)(seg + r + 4);   // rows r+4..r+7
    const int4 sgC = *(const int4*)(seg + r + 8);   // rows r+8..r+11
    const int4 sgD = *(const int4*)(seg + r + 12);  // rows r+12..r+15
    // 8 independent 1KB loads in flight before any RMW
    const float4 v0 = x4[(size_t)(r + 0 + h) * 32 + g];
    const float4 v1 = x4[(size_t)(r + 2 + h) * 32 + g];
    const float4 v2 = x4[(size_t)(r + 4 + h) * 32 + g];
    const float4 v3 = x4[(size_t)(r + 6 + h) * 32 + g];
    const float4 v4 = x4[(size_t)(r + 8 + h) * 32 + g];
    const float4 v5 = x4[(size_t)(r + 10 + h) * 32 + g];
    const float4 v6 = x4[(size_t)(r + 12 + h) * 32 + g];
    const float4 v7 = x4[(size_t)(r + 14 + h) * 32 + g];
    const int s0 = h ? sgA.y : sgA.x;
    const int s1 = h ? sgA.w : sgA.z;
    const int s2 = h ? sgB.y : sgB.x;
    const int s3 = h ? sgB.w : sgB.z;
    const int s4 = h ? sgC.y : sgC.x;
    const int s5 = h ? sgC.w : sgC.z;
    const int s6 = h ? sgD.y : sgD.x;
    const int s7 = h ? sgD.w : sgD.z;
    RMW(s0, v0)
    RMW(s1, v1)
    RMW(s2, v2)
    RMW(s3, v3)
    RMW(s4, v4)
    RMW(s5, v5)
    RMW(s6, v6)
    RMW(s7, v7)
  }
#undef RMW
  __syncthreads();

  for (int i = tid; i < rowsPerBlock; i += 256)
    atomicAdd(&lcnt[seg[blockIdx.x * rowsPerBlock + i]], 1.f);
  __syncthreads();

  float* outp = partials + (size_t)blockIdx.x * PENT;
  if (tid < NDOM) outp[tid] = lcnt[tid];
  for (int i = tid; i < 2 * NDOM * DIM; i += 256) {
    float v = 0.f;
#pragma unroll
    for (int rr = 0; rr < 8; ++rr) v += acc[rr * WREG + i];
    outp[NDOM + i] = v;
  }
}

// ---------------- pass 2: direct NB->stats (replaces reduce2 + finalize) ----------------
// 4 blocks x 256 threads = 1024 threads, one per (k,d). Each reads its slice
// of all NB partial rows (coalesced across threads, L2-resident: 4.2MB total)
// and writes the scale/shift table. One launch instead of two.
__global__ __launch_bounds__(256) void pn_stats(const float* __restrict__ partials,
                                                const float* __restrict__ gg,
                                                const float* __restrict__ gb,
                                                const float* __restrict__ dg,
                                                const float* __restrict__ db,
                                                float* __restrict__ stats, int NB) {
  const int t = blockIdx.x * 256 + threadIdx.x;  // 0..1023: (k = t>>7, d = t&127)
  const int k = t >> 7;
  const int d = t & (DIM - 1);
  float c = 0.f, s = 0.f, q = 0.f;
  for (int j = 0; j < NB; ++j) {
    const float* p = partials + (size_t)j * PENT;
    c += p[k];  // same line for whole wave (broadcast)
    s += p[NDOM + t];
    q += p[NDOM + NDOM * DIM + t];
  }
  const float n = fmaxf(c, 1.f);
  const float mean = s / n;
  const float var = fmaxf(q / n - mean * mean, 0.f);
  const float rstd = rsqrtf(var + EPSV);
  const float scale = (gg[d] + dg[t]) * rstd;  // dg[k*128+d] == dg[t]
  const float shift = (gb[d] + db[t]) - scale * mean;
  stats[t] = scale;
  stats[NDOM * DIM + t] = shift;
}

// ---------------- pass 3: normalize (one-shot, 1 float4/thread) ----------------
__global__ __launch_bounds__(256) void pn_apply(const float* __restrict__ x,
                                                const int* __restrict__ seg,
                                                const float* __restrict__ stats,
                                                float* __restrict__ out) {
  const int g = blockIdx.x * 256 + threadIdx.x;  // float4 index
  const int row = g >> 5;                        // 32 float4 per row
  const int c4 = g & 31;
  const int s = seg[row];
  const float4 xv = ((const float4*)x)[g];
  const float4 a = ((const float4*)(stats + s * DIM))[c4];
  const float4 b = ((const float4*)(stats + NDOM * DIM + s * DIM))[c4];
  float4 o;
  o.x = fmaf(xv.x, a.x, b.x);
  o.y = fmaf(xv.y, a.y, b.y);
  o.z = fmaf(xv.z, a.z, b.z);
  o.w = fmaf(xv.w, a.w, b.w);
  ((float4*)out)[g] = o;
}

extern "C" void kernel_launch(void* const* d_in, const int* in_sizes, int n_in,
                              void* d_out, int out_size, void* d_ws, size_t ws_size,
                              hipStream_t stream) {
  const float* x = (const float*)d_in[0];
  const float* gg = (const float*)d_in[1];
  const float* gb = (const float*)d_in[2];
  const float* dg = (const float*)d_in[3];
  const float* db = (const float*)d_in[4];
  const int* seg = (const int*)d_in[5];
  float* out = (float*)d_out;
  const int B = in_sizes[5];  // 262144

  // workspace: partials[NB][PENT] | stats[2048]
  const int NB = 512;  // 2 blocks/CU, one co-resident round
  float* partials = (float*)d_ws;
  float* stats = partials + (size_t)NB * PENT;

  const int rpb = B / NB;  // 512 rows/block; 128 contiguous rows/wave

  pn_reduce<<<NB, 256, 0, stream>>>((const float4*)x, seg, partials, rpb);
  pn_stats<<<4, 256, 0, stream>>>(partials, gg, gb, dg, db, stats, NB);

  const int nblk = (B * (DIM / 4)) / 256;  // 32768
  pn_apply<<<nblk, 256, 0, stream>>>(x, seg, stats, out);
}

// Round 24
// 89.853 us; speedup vs baseline: 2.4394x; 2.4394x over previous
//
#include <hip/hip_runtime.h>
#include <hip/hip_bf16.h>

// PartitionedNormalization: per-domain BN stats (training mode) + affine.
// out[B][128] f32 = (gg+dg[s])*(x-mean[s])*rsqrt(var[s]+eps) + (gb+db[s])
//
// R24 = R18 verbatim (session best, 90.88us). R23's merged pn_stats
// reverted: 4-block stats kernel = 150us (16 waves chip-wide, 512-deep
// serial load chain — parallelism collapse, not launch overhead, was
// the cost). reduce2(64 blk) + finalize(4 blk) restored.

#define DIM 128
#define NDOM 8
#define PENT (NDOM + 2 * NDOM * DIM)  // 8 counts + 1024 sums + 1024 sqsums = 2056
#define EPSV 1e-3f
#define WREG 2048  // per half-wave region (floats): sums[8][128] | sqs[8][128]

// ---------------- pass 1: half-wave-private LDS accumulation ----------------
__global__ __launch_bounds__(256) void pn_reduce(const float4* __restrict__ x4,
                                                 const int* __restrict__ seg,
                                                 float* __restrict__ partials,
                                                 int rowsPerBlock) {
  __shared__ float acc[8 * WREG];  // 64 KB -> 2 blocks/CU
  __shared__ float lcnt[NDOM];
  const int tid = threadIdx.x;
  const int w = tid >> 6;  // wave 0..3
  const int l = tid & 63;
  const int h = l >> 5;    // half-wave: row parity
  const int g = l & 31;    // float4 col group
  float* reg = acc + (w * 2 + h) * WREG;  // half-wave private

  for (int i = tid; i < 2 * WREG; i += 256)
    ((float4*)acc)[i] = make_float4(0.f, 0.f, 0.f, 0.f);
  if (tid < NDOM) lcnt[tid] = 0.f;
  __syncthreads();

  const int rowsPerWave = rowsPerBlock >> 2;  // 128 at NB=512
  const int row0 = blockIdx.x * rowsPerBlock + w * rowsPerWave;

#define RMW(S, V)                                    \
  {                                                  \
    float* bs = reg + (S) * 128 + g * 4;             \
    float* bq = bs + NDOM * DIM;                     \
    float4 os = *(float4*)bs;                        \
    float4 oq = *(float4*)bq;                        \
    os.x += (V).x;                                   \
    os.y += (V).y;                                   \
    os.z += (V).z;                                   \
    os.w += (V).w;                                   \
    oq.x = fmaf((V).x, (V).x, oq.x);                 \
    oq.y = fmaf((V).y, (V).y, oq.y);                 \
    oq.z = fmaf((V).z, (V).z, oq.z);                 \
    oq.w = fmaf((V).w, (V).w, oq.w);                 \
    *(float4*)bs = os;                               \
    *(float4*)bq = oq;                               \
  }
  for (int it = 0; it < rowsPerWave; it += 16) {
    const int r = row0 + it;
    const int4 sgA = *(const int4*)(seg + r);       // rows r..r+3
    const int4 sgB = *(const int4*)(seg + r + 4);   // rows r+4..r+7
    const int4 sgC = *(const int4*)(seg + r + 8);   // rows r+8..r+11
    const int4 sgD = *(const int4*)(seg + r + 12);  // rows r+12..r+15
    // 8 independent 1KB loads in flight before any RMW
    const float4 v0 = x4[(size_t)(r + 0 + h) * 32 + g];
    const float4 v1 = x4[(size_t)(r + 2 + h) * 32 + g];
    const float4 v2 = x4[(size_t)(r + 4 + h) * 32 + g];
    const float4 v3 = x4[(size_t)(r + 6 + h) * 32 + g];
    const float4 v4 = x4[(size_t)(r + 8 + h) * 32 + g];
    const float4 v5 = x4[(size_t)(r + 10 + h) * 32 + g];
    const float4 v6 = x4[(size_t)(r + 12 + h) * 32 + g];
    const float4 v7 = x4[(size_t)(r + 14 + h) * 32 + g];
    const int s0 = h ? sgA.y : sgA.x;
    const int s1 = h ? sgA.w : sgA.z;
    const int s2 = h ? sgB.y : sgB.x;
    const int s3 = h ? sgB.w : sgB.z;
    const int s4 = h ? sgC.y : sgC.x;
    const int s5 = h ? sgC.w : sgC.z;
    const int s6 = h ? sgD.y : sgD.x;
    const int s7 = h ? sgD.w : sgD.z;
    RMW(s0, v0)
    RMW(s1, v1)
    RMW(s2, v2)
    RMW(s3, v3)
    RMW(s4, v4)
    RMW(s5, v5)
    RMW(s6, v6)
    RMW(s7, v7)
  }
#undef RMW
  __syncthreads();

  for (int i = tid; i < rowsPerBlock; i += 256)
    atomicAdd(&lcnt[seg[blockIdx.x * rowsPerBlock + i]], 1.f);
  __syncthreads();

  float* outp = partials + (size_t)blockIdx.x * PENT;
  if (tid < NDOM) outp[tid] = lcnt[tid];
  for (int i = tid; i < 2 * NDOM * DIM; i += 256) {
    float v = 0.f;
#pragma unroll
    for (int rr = 0; rr < 8; ++rr) v += acc[rr * WREG + i];
    outp[NDOM + i] = v;
  }
}

// ---------------- pass 2a: reduce NB partial rows -> 64 ----------------
__global__ __launch_bounds__(256) void pn_reduce2(const float* __restrict__ partials,
                                                  float* __restrict__ partials2,
                                                  int NB) {
  const int b = blockIdx.x;  // 0..63
  const int per = NB >> 6;
  const int b0 = b * per;
  const int tid = threadIdx.x;
  float acc[9];
#pragma unroll
  for (int i = 0; i < 9; ++i) acc[i] = 0.f;
  for (int j = b0; j < b0 + per; ++j) {
    const float* p = partials + (size_t)j * PENT;
#pragma unroll
    for (int i = 0; i < 9; ++i) {
      const int e = tid + i * 256;
      if (e < PENT) acc[i] += p[e];
    }
  }
  float* o = partials2 + (size_t)b * PENT;
#pragma unroll
  for (int i = 0; i < 9; ++i) {
    const int e = tid + i * 256;
    if (e < PENT) o[e] = acc[i];
  }
}

// ---------------- pass 2b: final reduce + scale/shift table (4 blocks) ----------------
__global__ __launch_bounds__(256) void pn_finalize(const float* __restrict__ partials2,
                                                   const float* __restrict__ gg,
                                                   const float* __restrict__ gb,
                                                   const float* __restrict__ dg,
                                                   const float* __restrict__ db,
                                                   float* __restrict__ stats) {
  const int t = blockIdx.x * 256 + threadIdx.x;  // (k = t>>7, d = t&127)
  const int k = t >> 7;
  const int d = t & (DIM - 1);
  float c = 0.f, s = 0.f, q = 0.f;
  for (int j = 0; j < 64; ++j) {
    const float* p = partials2 + (size_t)j * PENT;
    c += p[k];
    s += p[NDOM + t];
    q += p[NDOM + NDOM * DIM + t];
  }
  const float n = fmaxf(c, 1.f);
  const float mean = s / n;
  const float var = fmaxf(q / n - mean * mean, 0.f);
  const float rstd = rsqrtf(var + EPSV);
  const float scale = (gg[d] + dg[t]) * rstd;  // dg[k*128+d] == dg[t]
  const float shift = (gb[d] + db[t]) - scale * mean;
  stats[t] = scale;
  stats[NDOM * DIM + t] = shift;
}

// ---------------- pass 3: normalize (one-shot, 1 float4/thread) ----------------
__global__ __launch_bounds__(256) void pn_apply(const float* __restrict__ x,
                                                const int* __restrict__ seg,
                                                const float* __restrict__ stats,
                                                float* __restrict__ out) {
  const int g = blockIdx.x * 256 + threadIdx.x;  // float4 index
  const int row = g >> 5;                        // 32 float4 per row
  const int c4 = g & 31;
  const int s = seg[row];
  const float4 xv = ((const float4*)x)[g];
  const float4 a = ((const float4*)(stats + s * DIM))[c4];
  const float4 b = ((const float4*)(stats + NDOM * DIM + s * DIM))[c4];
  float4 o;
  o.x = fmaf(xv.x, a.x, b.x);
  o.y = fmaf(xv.y, a.y, b.y);
  o.z = fmaf(xv.z, a.z, b.z);
  o.w = fmaf(xv.w, a.w, b.w);
  ((float4*)out)[g] = o;
}

extern "C" void kernel_launch(void* const* d_in, const int* in_sizes, int n_in,
                              void* d_out, int out_size, void* d_ws, size_t ws_size,
                              hipStream_t stream) {
  const float* x = (const float*)d_in[0];
  const float* gg = (const float*)d_in[1];
  const float* gb = (const float*)d_in[2];
  const float* dg = (const float*)d_in[3];
  const float* db = (const float*)d_in[4];
  const int* seg = (const int*)d_in[5];
  float* out = (float*)d_out;
  const int B = in_sizes[5];  // 262144

  // workspace: partials[NB][PENT] | partials2[64][PENT] | stats[2048]
  const int NB = 512;  // 2 blocks/CU, one co-resident round
  float* partials = (float*)d_ws;
  float* partials2 = partials + (size_t)NB * PENT;
  float* stats = partials2 + (size_t)64 * PENT;

  const int rpb = B / NB;  // 512 rows/block; 128 contiguous rows/wave

  pn_reduce<<<NB, 256, 0, stream>>>((const float4*)x, seg, partials, rpb);
  pn_reduce2<<<64, 256, 0, stream>>>(partials, partials2, NB);
  pn_finalize<<<4, 256, 0, stream>>>(partials2, gg, gb, dg, db, stats);

  const int nblk = (B * (DIM / 4)) / 256;  // 32768
  pn_apply<<<nblk, 256, 0, stream>>>(x, seg, stats, out);
}